// Round 13
// baseline (233.962 us; speedup 1.0000x reference)
//
#include <hip/hip_runtime.h>
#include <math.h>

// DigitCaps dynamic routing via MFMA u_hat + fused in-register routing.
// R13: R12 inner loop byte-identical; occupancy x2 via NIC=32 (grid 1024 =
//      4 blocks/CU; 104 VGPR permits 4 waves/SIMD). NIC%8==0 keeps XCD
//      affinity (same-icb blocks 32 apart -> same XCD L2 holds the W window).
#define J 10
#define BT 16          // batch tile (MFMA N)
#define NBT 32         // BATCH/BT
#define NIC 32         // i-chunks; NIC%8==0 -> same-icb blocks on one XCD
#define ICB 36         // IN_CAPS/NIC
#define IPW 9          // i per wave (4 waves/block)
#define JD 160
#define BATCH 512
#define IN_CAPS 1152
#define RTH 256

typedef __attribute__((ext_vector_type(8))) short short8;
typedef __attribute__((ext_vector_type(4))) float f32x4;

__device__ inline short f2bf(float f) {
    union { float f; unsigned u; } v; v.f = f;
    return (short)((v.u + 0x7FFFu + ((v.u >> 16) & 1u)) >> 16);  // RNE
}
__device__ inline short8 cvt8(float4 a, float4 b) {
    short8 o;
    o[0] = f2bf(a.x); o[1] = f2bf(a.y); o[2] = f2bf(a.z); o[3] = f2bf(a.w);
    o[4] = f2bf(b.x); o[5] = f2bf(b.y); o[6] = f2bf(b.z); o[7] = f2bf(b.w);
    return o;
}

// W fp32 -> bf16 (same [i][j][d][e] layout), and zero pad-buffer.
__global__ __launch_bounds__(256) void convert_w(
    const float* __restrict__ W, short* __restrict__ Wb, short* __restrict__ zb)
{
    const int t = blockIdx.x * 256 + threadIdx.x;   // 184320 threads exactly
    const float4* src = (const float4*)W + (size_t)t * 2;
    *(short8*)(Wb + (size_t)t * 8) = cvt8(src[0], src[1]);
    if (blockIdx.x == 0 && threadIdx.x < 32) zb[threadIdx.x] = 0;
}

// X fp32 [b][i][e] -> bf16 Xb [i][b][e] (LDS-tiled transpose).
#define TI 32
#define TB 64
__global__ __launch_bounds__(256) void transpose_x(
    const float* __restrict__ X, short* __restrict__ Xb)
{
    __shared__ short8 tile[TI][TB + 1];
    const int it = blockIdx.x % (IN_CAPS / TI);   // 36 i-tiles
    const int bt = blockIdx.x / (IN_CAPS / TI);   // 8 b-tiles
    const int t  = threadIdx.x;

    const int i_l = t & 31, b_s = t >> 5;         // load: 8 b x 32 i per pass
#pragma unroll
    for (int p = 0; p < 8; ++p) {
        const int b_l = p * 8 + b_s;
        const float4* src = (const float4*)(X +
            (((size_t)(bt * TB + b_l)) * IN_CAPS + it * TI + i_l) * 8);
        tile[i_l][b_l] = cvt8(src[0], src[1]);
    }
    __syncthreads();
    const int b_l = t & 63, i_s = t >> 6;         // store: 4 i x 64 b per pass
#pragma unroll
    for (int p = 0; p < 8; ++p) {
        const int i_l2 = p * 4 + i_s;
        *(short8*)(Xb + (((size_t)(it * TI + i_l2)) * BATCH + bt * TB + b_l) * 8)
            = tile[i_l2][b_l];
    }
}

// MFMA orientation (verified R3-R12): A = W (M=16 d of one j), B = X (N=16 b), K = e.
// A[row=bcol(d)][k=kg*8+e], B[k=kg*8+e][col=bcol(b)], C: col=lane&15=b, row=(lane>>4)*4+reg=d.
// MODE 0: c = 0.1 (K=32 GEMM: 4 i x 8 e).
// MODE 1: 4-i packed loads; per-i u via B-mask (kg==t), logits from V, softmax, s.
template<int MODE>
__global__ __launch_bounds__(RTH, 2) void route_kernel(
    const short* __restrict__ Xb, const short* __restrict__ Wb,
    const short* __restrict__ zb, const float* __restrict__ V,
    float* __restrict__ S_part)
{
    __shared__ float s_lds[BT][JD + 1];
    const int tid   = threadIdx.x;
    const int lane  = tid & 63, wave = tid >> 6;
    const int icb   = blockIdx.x % NIC;
    const int btile = blockIdx.x / NIC;
    const int bcol  = lane & 15, kg = lane >> 4;
    const int b     = btile * BT + bcol;

    for (int t = tid; t < BT * (JD + 1); t += RTH) (&s_lds[0][0])[t] = 0.f;
    __syncthreads();

    if (MODE == 0) {
        f32x4 acc[J];
#pragma unroll
        for (int j = 0; j < J; ++j) acc[j] = (f32x4)(0.f);
        for (int ks = wave; ks < ICB / 4; ks += 4) {
            const int ia = icb * ICB + ks * 4 + kg;     // lane's i (k-group)
            const short8 bfr = *(const short8*)(Xb + ((size_t)ia * BATCH + b) * 8);
            short8 afr[J];
#pragma unroll
            for (int j = 0; j < J; ++j)
                afr[j] = *(const short8*)(Wb + (size_t)ia * 1280 + j * 128 + bcol * 8);
#pragma unroll
            for (int j = 0; j < J; ++j)
                acc[j] = __builtin_amdgcn_mfma_f32_16x16x32_bf16(afr[j], bfr, acc[j], 0, 0, 0);
        }
#pragma unroll
        for (int j = 0; j < J; ++j)
#pragma unroll
            for (int r = 0; r < 4; ++r)
                atomicAdd(&s_lds[bcol][j * 16 + kg * 4 + r], 0.1f * acc[j][r]);
    } else {
        float4 Vr[J];
#pragma unroll
        for (int j = 0; j < J; ++j)
            Vr[j] = *(const float4*)(V + (size_t)b * JD + j * 16 + kg * 4);

        float s_acc[J][4];
#pragma unroll
        for (int j = 0; j < J; ++j)
#pragma unroll
            for (int r = 0; r < 4; ++r) s_acc[j][r] = 0.f;

        const int i0w = icb * ICB + wave * IPW;
        const short8 zero8 = (short8)(short)0;

        // 3 groups: 2 full (4 i each) + 1 tail (1 i). Loads are 4-i packed:
        // lane kg carries i = ibase + kg for ALL 64 lanes (no zero-lane waste).
#pragma unroll
        for (int g = 0; g < 3; ++g) {
            const int nt = (g < 2) ? 4 : 1;           // sub-steps this group
            int ia = i0w + g * 4 + kg;
            if (ia > IN_CAPS - 1) ia = IN_CAPS - 1;   // tail clamp (masked away)

            short8 afr[J];
#pragma unroll
            for (int j = 0; j < J; ++j)
                afr[j] = *(const short8*)(Wb + (size_t)ia * 1280 + j * 128 + bcol * 8);
            const short8 bfull = *(const short8*)(Xb + ((size_t)ia * BATCH + b) * 8);

            for (int t = 0; t < nt; ++t) {
                // B-mask: zero outside k-block t -> MFMA yields u for i_t only
                const short8 bt = (kg == t) ? bfull : zero8;
                f32x4 u[J];
#pragma unroll
                for (int j = 0; j < J; ++j)
                    u[j] = __builtin_amdgcn_mfma_f32_16x16x32_bf16(afr[j], bt, (f32x4)(0.f), 0, 0, 0);

                // logits: 4 in-register FMA + 2-step xor reduce over kg replicas
                float L[J];
#pragma unroll
                for (int j = 0; j < J; ++j)
                    L[j] = u[j][0] * Vr[j].x + u[j][1] * Vr[j].y
                         + u[j][2] * Vr[j].z + u[j][3] * Vr[j].w;
#pragma unroll
                for (int j = 0; j < J; ++j) {
                    L[j] += __shfl_xor(L[j], 16);
                    L[j] += __shfl_xor(L[j], 32);
                }
                // softmax over j (logits bounded, |L| < 1: no max-sub needed)
                float c[J], Z = 0.f;
#pragma unroll
                for (int j = 0; j < J; ++j) { c[j] = __expf(L[j]); Z += c[j]; }
                const float rz = 1.0f / Z;
#pragma unroll
                for (int j = 0; j < J; ++j) {
                    const float cj = c[j] * rz;
                    s_acc[j][0] += cj * u[j][0];
                    s_acc[j][1] += cj * u[j][1];
                    s_acc[j][2] += cj * u[j][2];
                    s_acc[j][3] += cj * u[j][3];
                }
            }
        }
#pragma unroll
        for (int j = 0; j < J; ++j)
#pragma unroll
            for (int r = 0; r < 4; ++r)
                atomicAdd(&s_lds[bcol][j * 16 + kg * 4 + r], s_acc[j][r]);
    }
    __syncthreads();

    for (int t = tid; t < BT * JD; t += RTH) {
        const int bb = t / JD, p = t % JD;
        S_part[((size_t)icb * BATCH + btile * BT + bb) * JD + p] = s_lds[bb][p];
    }
}

// mode: 0 -> V = v, 1 -> V += v, 2 -> out = v
__global__ __launch_bounds__(256) void squash_kernel(
    const float* __restrict__ S_part, float* __restrict__ V,
    float* __restrict__ out, int mode)
{
    const int t = blockIdx.x * 256 + threadIdx.x;  // BATCH*JD threads
    float s = 0.f;
#pragma unroll
    for (int ic = 0; ic < NIC; ic++)
        s += S_part[(size_t)ic * BATCH * JD + t];
    float sq = s * s;
    sq += __shfl_xor(sq, 1);
    sq += __shfl_xor(sq, 2);
    sq += __shfl_xor(sq, 4);
    sq += __shfl_xor(sq, 8);
    const float v = s * sq / ((1.f + sq) * sqrtf(sq + 1e-8f));
    if (mode == 0)      V[t] = v;
    else if (mode == 1) V[t] += v;
    else                out[t] = v;
}

extern "C" void kernel_launch(void* const* d_in, const int* in_sizes, int n_in,
                              void* d_out, int out_size, void* d_ws, size_t ws_size,
                              hipStream_t stream)
{
    const float* X = (const float*)d_in[0];   // [512][1152][8]
    const float* W = (const float*)d_in[1];   // [1152][10][16][8]
    float* out = (float*)d_out;               // [512][10][16]

    // ws: S_part[32][512][160] f32 (10.5MB) | V[512][160] f32 | Wb bf16 (2.95MB)
    //   | Xb bf16 [1152][512][8] (9.44MB) | zb (64B zeros)   total ~23.2 MB
    float* S_part = (float*)d_ws;
    float* V      = S_part + (size_t)NIC * BATCH * JD;
    short* Wb     = (short*)(V + (size_t)BATCH * JD);
    short* Xb     = Wb + (size_t)IN_CAPS * JD * 8;
    short* zb     = Xb + (size_t)IN_CAPS * BATCH * 8;

    const dim3 rg(NBT * NIC), rb(RTH);        // 1024 blocks x 4 waves = 4/CU
    const dim3 sg(BATCH * JD / 256), sb(256); // 320 blocks

    convert_w<<<dim3(720), dim3(256), 0, stream>>>(W, Wb, zb);
    transpose_x<<<dim3((IN_CAPS / TI) * (BATCH / TB)), dim3(256), 0, stream>>>(X, Xb);

    route_kernel<0><<<rg, rb, 0, stream>>>(Xb, Wb, zb, V, S_part);
    squash_kernel<<<sg, sb, 0, stream>>>(S_part, V, out, 0);   // V = v0
    route_kernel<1><<<rg, rb, 0, stream>>>(Xb, Wb, zb, V, S_part);
    squash_kernel<<<sg, sb, 0, stream>>>(S_part, V, out, 1);   // V += v1
    route_kernel<1><<<rg, rb, 0, stream>>>(Xb, Wb, zb, V, S_part);
    squash_kernel<<<sg, sb, 0, stream>>>(S_part, V, out, 2);   // out = v2
}

// Round 14
// 156.600 us; speedup vs baseline: 1.4940x; 1.4940x over previous
//
#include <hip/hip_runtime.h>
#include <math.h>

// DigitCaps dynamic routing via MFMA u_hat + fused in-register routing.
// R14: R12 base; mode-1 group restructured into 3 wide phases:
//      (1) 4x independent masked-MFMA logit sub-steps (u dies at the dot),
//      (2) 4x independent softmaxes + kg-select of c,
//      (3) ONE packed K=32 MFMA per j with B' = bf16(c*x)  (s in MFMA acc).
#define J 10
#define BT 16          // batch tile (MFMA N)
#define NBT 32         // BATCH/BT
#define NIC 16         // i-chunks; NIC%8==0 -> same-icb blocks on one XCD
#define ICB 72         // IN_CAPS/NIC
#define IPW 18         // i per wave (4 waves/block)
#define JD 160
#define BATCH 512
#define IN_CAPS 1152
#define RTH 256

typedef __attribute__((ext_vector_type(8))) short short8;
typedef __attribute__((ext_vector_type(4))) float f32x4;
typedef __attribute__((ext_vector_type(4))) unsigned uint4v;

__device__ inline short f2bf(float f) {
    union { float f; unsigned u; } v; v.f = f;
    return (short)((v.u + 0x7FFFu + ((v.u >> 16) & 1u)) >> 16);  // RNE
}
__device__ inline short8 cvt8(float4 a, float4 b) {
    short8 o;
    o[0] = f2bf(a.x); o[1] = f2bf(a.y); o[2] = f2bf(a.z); o[3] = f2bf(a.w);
    o[4] = f2bf(b.x); o[5] = f2bf(b.y); o[6] = f2bf(b.z); o[7] = f2bf(b.w);
    return o;
}
__device__ inline float bf2f(short s) {
    union { unsigned u; float f; } v; v.u = ((unsigned)(unsigned short)s) << 16;
    return v.f;
}

// W fp32 -> bf16 (same [i][j][d][e] layout), and zero pad-buffer.
__global__ __launch_bounds__(256) void convert_w(
    const float* __restrict__ W, short* __restrict__ Wb, short* __restrict__ zb)
{
    const int t = blockIdx.x * 256 + threadIdx.x;   // 184320 threads exactly
    const float4* src = (const float4*)W + (size_t)t * 2;
    *(short8*)(Wb + (size_t)t * 8) = cvt8(src[0], src[1]);
    if (blockIdx.x == 0 && threadIdx.x < 32) zb[threadIdx.x] = 0;
}

// X fp32 [b][i][e] -> bf16 Xb [i][b][e] (LDS-tiled transpose).
#define TI 32
#define TB 64
__global__ __launch_bounds__(256) void transpose_x(
    const float* __restrict__ X, short* __restrict__ Xb)
{
    __shared__ short8 tile[TI][TB + 1];
    const int it = blockIdx.x % (IN_CAPS / TI);   // 36 i-tiles
    const int bt = blockIdx.x / (IN_CAPS / TI);   // 8 b-tiles
    const int t  = threadIdx.x;

    const int i_l = t & 31, b_s = t >> 5;         // load: 8 b x 32 i per pass
#pragma unroll
    for (int p = 0; p < 8; ++p) {
        const int b_l = p * 8 + b_s;
        const float4* src = (const float4*)(X +
            (((size_t)(bt * TB + b_l)) * IN_CAPS + it * TI + i_l) * 8);
        tile[i_l][b_l] = cvt8(src[0], src[1]);
    }
    __syncthreads();
    const int b_l = t & 63, i_s = t >> 6;         // store: 4 i x 64 b per pass
#pragma unroll
    for (int p = 0; p < 8; ++p) {
        const int i_l2 = p * 4 + i_s;
        *(short8*)(Xb + (((size_t)(it * TI + i_l2)) * BATCH + bt * TB + b_l) * 8)
            = tile[i_l2][b_l];
    }
}

// MFMA orientation (verified R3-R13): A = W (M=16 d of one j), B = X (N=16 b), K = e.
// A[row=bcol(d)][k=kg*8+e], B[k=kg*8+e][col=bcol(b)], C: col=lane&15=b, row=(lane>>4)*4+reg=d.
// MODE 0: c = 0.1 (K=32 GEMM: 4 i x 8 e).
// MODE 1: 3-phase group (see header comment).
template<int MODE>
__global__ __launch_bounds__(RTH, 2) void route_kernel(
    const short* __restrict__ Xb, const short* __restrict__ Wb,
    const short* __restrict__ zb, const float* __restrict__ V,
    float* __restrict__ S_part)
{
    __shared__ float s_lds[BT][JD + 1];
    const int tid   = threadIdx.x;
    const int lane  = tid & 63, wave = tid >> 6;
    const int icb   = blockIdx.x % NIC;
    const int btile = blockIdx.x / NIC;
    const int bcol  = lane & 15, kg = lane >> 4;
    const int b     = btile * BT + bcol;

    for (int t = tid; t < BT * (JD + 1); t += RTH) (&s_lds[0][0])[t] = 0.f;
    __syncthreads();

    if (MODE == 0) {
        f32x4 acc[J];
#pragma unroll
        for (int j = 0; j < J; ++j) acc[j] = (f32x4)(0.f);
        for (int ks = wave; ks < ICB / 4; ks += 4) {
            const int ia = icb * ICB + ks * 4 + kg;     // lane's i (k-group)
            const short8 bfr = *(const short8*)(Xb + ((size_t)ia * BATCH + b) * 8);
            short8 afr[J];
#pragma unroll
            for (int j = 0; j < J; ++j)
                afr[j] = *(const short8*)(Wb + (size_t)ia * 1280 + j * 128 + bcol * 8);
#pragma unroll
            for (int j = 0; j < J; ++j)
                acc[j] = __builtin_amdgcn_mfma_f32_16x16x32_bf16(afr[j], bfr, acc[j], 0, 0, 0);
        }
#pragma unroll
        for (int j = 0; j < J; ++j)
#pragma unroll
            for (int r = 0; r < 4; ++r)
                atomicAdd(&s_lds[bcol][j * 16 + kg * 4 + r], 0.1f * acc[j][r]);
    } else {
        float4 Vr[J];
#pragma unroll
        for (int j = 0; j < J; ++j)
            Vr[j] = *(const float4*)(V + (size_t)b * JD + j * 16 + kg * 4);

        f32x4 acc[J];            // s accumulates in MFMA C operand
#pragma unroll
        for (int j = 0; j < J; ++j) acc[j] = (f32x4)(0.f);

        const int i0w = icb * ICB + wave * IPW;
        const short8 zero8 = (short8)(short)0;

        // 5 groups: 4 full (4 i) + 1 tail (2 i); loads 4-i packed.
#pragma unroll
        for (int g = 0; g < 5; ++g) {
            const int nt = (g < 4) ? 4 : 2;           // sub-steps this group
            int ia = i0w + g * 4 + kg;
            if (ia > IN_CAPS - 1) ia = IN_CAPS - 1;   // tail clamp (cSel=0 there)

            short8 afr[J];
#pragma unroll
            for (int j = 0; j < J; ++j)
                afr[j] = *(const short8*)(Wb + (size_t)ia * 1280 + j * 128 + bcol * 8);
            const short8 bfull = *(const short8*)(Xb + ((size_t)ia * BATCH + b) * 8);

            float xf[8];
#pragma unroll
            for (int e = 0; e < 8; ++e) xf[e] = bf2f(bfull[e]);

            // Phase 1: all sub-steps' masked MFMAs + logit dots (u dies here)
            float Lp[4][J];
#pragma unroll
            for (int t = 0; t < 4; ++t) {
                if (t < nt) {
                    const short8 bt = (kg == t) ? bfull : zero8;
#pragma unroll
                    for (int j = 0; j < J; ++j) {
                        const f32x4 u = __builtin_amdgcn_mfma_f32_16x16x32_bf16(
                            afr[j], bt, (f32x4)(0.f), 0, 0, 0);
                        Lp[t][j] = u[0] * Vr[j].x + u[1] * Vr[j].y
                                 + u[2] * Vr[j].z + u[3] * Vr[j].w;
                    }
                }
            }

            // Phase 2: reduce + softmax per sub-step; keep c only on kg==t lanes
            float cSel[J];
#pragma unroll
            for (int j = 0; j < J; ++j) cSel[j] = 0.f;
#pragma unroll
            for (int t = 0; t < 4; ++t) {
                if (t < nt) {
                    float c[J], Z = 0.f;
#pragma unroll
                    for (int j = 0; j < J; ++j) {
                        float l = Lp[t][j];
                        l += __shfl_xor(l, 16);
                        l += __shfl_xor(l, 32);
                        c[j] = __expf(l);             // logits bounded: no max-sub
                        Z += c[j];
                    }
                    const float rz = 1.0f / Z;
#pragma unroll
                    for (int j = 0; j < J; ++j) {
                        const float cv = c[j] * rz;
                        cSel[j] = (kg == t) ? cv : cSel[j];
                    }
                }
            }

            // Phase 3: one packed K=32 MFMA per j with B' = bf16(c * x)
#pragma unroll
            for (int j = 0; j < J; ++j) {
                const float cj = cSel[j];
                unsigned q0, q1, q2, q3;
                asm("v_cvt_pk_bf16_f32 %0, %1, %2" : "=v"(q0)
                    : "v"(xf[0] * cj), "v"(xf[1] * cj));
                asm("v_cvt_pk_bf16_f32 %0, %1, %2" : "=v"(q1)
                    : "v"(xf[2] * cj), "v"(xf[3] * cj));
                asm("v_cvt_pk_bf16_f32 %0, %1, %2" : "=v"(q2)
                    : "v"(xf[4] * cj), "v"(xf[5] * cj));
                asm("v_cvt_pk_bf16_f32 %0, %1, %2" : "=v"(q3)
                    : "v"(xf[6] * cj), "v"(xf[7] * cj));
                union { uint4v v; short8 s; } bu;
                bu.v = (uint4v){q0, q1, q2, q3};
                acc[j] = __builtin_amdgcn_mfma_f32_16x16x32_bf16(
                    afr[j], bu.s, acc[j], 0, 0, 0);
            }
        }
#pragma unroll
        for (int j = 0; j < J; ++j)
#pragma unroll
            for (int r = 0; r < 4; ++r)
                atomicAdd(&s_lds[bcol][j * 16 + kg * 4 + r], acc[j][r]);
    }
    __syncthreads();

    for (int t = tid; t < BT * JD; t += RTH) {
        const int bb = t / JD, p = t % JD;
        S_part[((size_t)icb * BATCH + btile * BT + bb) * JD + p] = s_lds[bb][p];
    }
}

// mode: 0 -> V = v, 1 -> V += v, 2 -> out = v
__global__ __launch_bounds__(256) void squash_kernel(
    const float* __restrict__ S_part, float* __restrict__ V,
    float* __restrict__ out, int mode)
{
    const int t = blockIdx.x * 256 + threadIdx.x;  // BATCH*JD threads
    float s = 0.f;
#pragma unroll
    for (int ic = 0; ic < NIC; ic++)
        s += S_part[(size_t)ic * BATCH * JD + t];
    float sq = s * s;
    sq += __shfl_xor(sq, 1);
    sq += __shfl_xor(sq, 2);
    sq += __shfl_xor(sq, 4);
    sq += __shfl_xor(sq, 8);
    const float v = s * sq / ((1.f + sq) * sqrtf(sq + 1e-8f));
    if (mode == 0)      V[t] = v;
    else if (mode == 1) V[t] += v;
    else                out[t] = v;
}

extern "C" void kernel_launch(void* const* d_in, const int* in_sizes, int n_in,
                              void* d_out, int out_size, void* d_ws, size_t ws_size,
                              hipStream_t stream)
{
    const float* X = (const float*)d_in[0];   // [512][1152][8]
    const float* W = (const float*)d_in[1];   // [1152][10][16][8]
    float* out = (float*)d_out;               // [512][10][16]

    // ws: S_part[16][512][160] f32 (5.24MB) | V[512][160] f32 | Wb bf16 (2.95MB)
    //   | Xb bf16 [1152][512][8] (9.44MB) | zb (64B zeros)   total ~18.0 MB
    float* S_part = (float*)d_ws;
    float* V      = S_part + (size_t)NIC * BATCH * JD;
    short* Wb     = (short*)(V + (size_t)BATCH * JD);
    short* Xb     = Wb + (size_t)IN_CAPS * JD * 8;
    short* zb     = Xb + (size_t)IN_CAPS * BATCH * 8;

    const dim3 rg(NBT * NIC), rb(RTH);        // 512 blocks x 4 waves
    const dim3 sg(BATCH * JD / 256), sb(256); // 320 blocks

    convert_w<<<dim3(720), dim3(256), 0, stream>>>(W, Wb, zb);
    transpose_x<<<dim3((IN_CAPS / TI) * (BATCH / TB)), dim3(256), 0, stream>>>(X, Xb);

    route_kernel<0><<<rg, rb, 0, stream>>>(Xb, Wb, zb, V, S_part);
    squash_kernel<<<sg, sb, 0, stream>>>(S_part, V, out, 0);   // V = v0
    route_kernel<1><<<rg, rb, 0, stream>>>(Xb, Wb, zb, V, S_part);
    squash_kernel<<<sg, sb, 0, stream>>>(S_part, V, out, 1);   // V += v1
    route_kernel<1><<<rg, rb, 0, stream>>>(Xb, Wb, zb, V, S_part);
    squash_kernel<<<sg, sb, 0, stream>>>(S_part, V, out, 2);   // out = v2
}

// Round 16
// 142.388 us; speedup vs baseline: 1.6431x; 1.0998x over previous
//
#include <hip/hip_runtime.h>
#include <math.h>

// DigitCaps dynamic routing via MFMA u_hat + fused in-register routing.
// R15b: R12 base; the ONLY change is the logit kg-reduce: 2x ds_bpermute per j
//       replaced by a chained f16 MFMA (ones x p) that sums d in the matrix
//       pipe and broadcasts L[b] to all lanes via the C-layout.
//       (compile fix vs R15: cvt_pkrtz returns __fp16x2, use __fp16 vectors)
#define J 10
#define BT 16          // batch tile (MFMA N)
#define NBT 32         // BATCH/BT
#define NIC 16         // i-chunks; NIC%8==0 -> same-icb blocks on one XCD
#define ICB 72         // IN_CAPS/NIC
#define IPW 18         // i per wave (4 waves/block)
#define JD 160
#define BATCH 512
#define IN_CAPS 1152
#define RTH 256

typedef __attribute__((ext_vector_type(8))) short short8;
typedef __attribute__((ext_vector_type(4))) float f32x4;
typedef __attribute__((ext_vector_type(4))) __fp16 fp16x4;
typedef __attribute__((ext_vector_type(2))) __fp16 fp16x2;

__device__ inline short f2bf(float f) {
    union { float f; unsigned u; } v; v.f = f;
    return (short)((v.u + 0x7FFFu + ((v.u >> 16) & 1u)) >> 16);  // RNE
}
__device__ inline short8 cvt8(float4 a, float4 b) {
    short8 o;
    o[0] = f2bf(a.x); o[1] = f2bf(a.y); o[2] = f2bf(a.z); o[3] = f2bf(a.w);
    o[4] = f2bf(b.x); o[5] = f2bf(b.y); o[6] = f2bf(b.z); o[7] = f2bf(b.w);
    return o;
}

// W fp32 -> bf16 (same [i][j][d][e] layout), and zero pad-buffer.
__global__ __launch_bounds__(256) void convert_w(
    const float* __restrict__ W, short* __restrict__ Wb, short* __restrict__ zb)
{
    const int t = blockIdx.x * 256 + threadIdx.x;   // 184320 threads exactly
    const float4* src = (const float4*)W + (size_t)t * 2;
    *(short8*)(Wb + (size_t)t * 8) = cvt8(src[0], src[1]);
    if (blockIdx.x == 0 && threadIdx.x < 32) zb[threadIdx.x] = 0;
}

// X fp32 [b][i][e] -> bf16 Xb [i][b][e] (LDS-tiled transpose).
#define TI 32
#define TB 64
__global__ __launch_bounds__(256) void transpose_x(
    const float* __restrict__ X, short* __restrict__ Xb)
{
    __shared__ short8 tile[TI][TB + 1];
    const int it = blockIdx.x % (IN_CAPS / TI);   // 36 i-tiles
    const int bt = blockIdx.x / (IN_CAPS / TI);   // 8 b-tiles
    const int t  = threadIdx.x;

    const int i_l = t & 31, b_s = t >> 5;         // load: 8 b x 32 i per pass
#pragma unroll
    for (int p = 0; p < 8; ++p) {
        const int b_l = p * 8 + b_s;
        const float4* src = (const float4*)(X +
            (((size_t)(bt * TB + b_l)) * IN_CAPS + it * TI + i_l) * 8);
        tile[i_l][b_l] = cvt8(src[0], src[1]);
    }
    __syncthreads();
    const int b_l = t & 63, i_s = t >> 6;         // store: 4 i x 64 b per pass
#pragma unroll
    for (int p = 0; p < 8; ++p) {
        const int i_l2 = p * 4 + i_s;
        *(short8*)(Xb + (((size_t)(it * TI + i_l2)) * BATCH + bt * TB + b_l) * 8)
            = tile[i_l2][b_l];
    }
}

// MFMA orientation (verified R3-R14): A = W (M=16 d of one j), B = X (N=16 b), K = e.
// C layout: col = lane&15 = b, row = (lane>>4)*4 + reg = d.
// MODE 0: c = 0.1 (K=32 GEMM: 4 i x 8 e).
// MODE 1: 4-i packed loads; per-i u via B-mask (kg==t); logit reduce via
//         chained 16x16x16 f16 MFMA (A=ones sums all k, C replicates L[b]).
template<int MODE>
__global__ __launch_bounds__(RTH, 2) void route_kernel(
    const short* __restrict__ Xb, const short* __restrict__ Wb,
    const short* __restrict__ zb, const float* __restrict__ V,
    float* __restrict__ S_part)
{
    __shared__ float s_lds[BT][JD + 1];
    const int tid   = threadIdx.x;
    const int lane  = tid & 63, wave = tid >> 6;
    const int icb   = blockIdx.x % NIC;
    const int btile = blockIdx.x / NIC;
    const int bcol  = lane & 15, kg = lane >> 4;
    const int b     = btile * BT + bcol;

    for (int t = tid; t < BT * (JD + 1); t += RTH) (&s_lds[0][0])[t] = 0.f;
    __syncthreads();

    if (MODE == 0) {
        f32x4 acc[J];
#pragma unroll
        for (int j = 0; j < J; ++j) acc[j] = (f32x4)(0.f);
        for (int ks = wave; ks < ICB / 4; ks += 4) {
            const int ia = icb * ICB + ks * 4 + kg;     // lane's i (k-group)
            const short8 bfr = *(const short8*)(Xb + ((size_t)ia * BATCH + b) * 8);
            short8 afr[J];
#pragma unroll
            for (int j = 0; j < J; ++j)
                afr[j] = *(const short8*)(Wb + (size_t)ia * 1280 + j * 128 + bcol * 8);
#pragma unroll
            for (int j = 0; j < J; ++j)
                acc[j] = __builtin_amdgcn_mfma_f32_16x16x32_bf16(afr[j], bfr, acc[j], 0, 0, 0);
        }
#pragma unroll
        for (int j = 0; j < J; ++j)
#pragma unroll
            for (int r = 0; r < 4; ++r)
                atomicAdd(&s_lds[bcol][j * 16 + kg * 4 + r], 0.1f * acc[j][r]);
    } else {
        float4 Vr[J];
#pragma unroll
        for (int j = 0; j < J; ++j)
            Vr[j] = *(const float4*)(V + (size_t)b * JD + j * 16 + kg * 4);

        float s_acc[J][4];
#pragma unroll
        for (int j = 0; j < J; ++j)
#pragma unroll
            for (int r = 0; r < 4; ++r) s_acc[j][r] = 0.f;

        fp16x4 ones;
        ones[0] = (__fp16)1.0f; ones[1] = (__fp16)1.0f;
        ones[2] = (__fp16)1.0f; ones[3] = (__fp16)1.0f;

        const int i0w = icb * ICB + wave * IPW;
        const short8 zero8 = (short8)(short)0;

        // 5 groups: 4 full (4 i each) + 1 tail (2 i). Loads are 4-i packed:
        // lane kg carries i = ibase + kg for ALL 64 lanes (no zero-lane waste).
#pragma unroll
        for (int g = 0; g < 5; ++g) {
            const int nt = (g < 4) ? 4 : 2;           // sub-steps this group
            int ia = i0w + g * 4 + kg;
            if (ia > IN_CAPS - 1) ia = IN_CAPS - 1;   // tail clamp (masked away)

            short8 afr[J];
#pragma unroll
            for (int j = 0; j < J; ++j)
                afr[j] = *(const short8*)(Wb + (size_t)ia * 1280 + j * 128 + bcol * 8);
            const short8 bfull = *(const short8*)(Xb + ((size_t)ia * BATCH + b) * 8);

            for (int t = 0; t < nt; ++t) {
                // B-mask: zero outside k-block t -> MFMA yields u for i_t only
                const short8 bt = (kg == t) ? bfull : zero8;
                f32x4 u[J];
#pragma unroll
                for (int j = 0; j < J; ++j)
                    u[j] = __builtin_amdgcn_mfma_f32_16x16x32_bf16(afr[j], bt, (f32x4)(0.f), 0, 0, 0);

                // logit reduce via chained MFMA: p = u*V (4 FMA), pack f16,
                // mfma(ones, p): sums ALL k (= all d across kg) per column b
                // and replicates the result to every lane of that column.
                float L[J];
#pragma unroll
                for (int j = 0; j < J; ++j) {
                    const float p0 = u[j][0] * Vr[j].x;
                    const float p1 = u[j][1] * Vr[j].y;
                    const float p2 = u[j][2] * Vr[j].z;
                    const float p3 = u[j][3] * Vr[j].w;
                    const fp16x2 a01 = __builtin_amdgcn_cvt_pkrtz(p0, p1);
                    const fp16x2 a23 = __builtin_amdgcn_cvt_pkrtz(p2, p3);
                    fp16x4 pb;
                    pb[0] = a01[0]; pb[1] = a01[1];
                    pb[2] = a23[0]; pb[3] = a23[1];
                    const f32x4 Lr = __builtin_amdgcn_mfma_f32_16x16x16f16(
                        ones, pb, (f32x4)(0.f), 0, 0, 0);
                    L[j] = Lr[0];
                }
                // softmax over j (logits bounded, |L| < 1: no max-sub needed)
                float c[J], Z = 0.f;
#pragma unroll
                for (int j = 0; j < J; ++j) { c[j] = __expf(L[j]); Z += c[j]; }
                const float rz = 1.0f / Z;
#pragma unroll
                for (int j = 0; j < J; ++j) {
                    const float cj = c[j] * rz;
                    s_acc[j][0] += cj * u[j][0];
                    s_acc[j][1] += cj * u[j][1];
                    s_acc[j][2] += cj * u[j][2];
                    s_acc[j][3] += cj * u[j][3];
                }
            }
        }
#pragma unroll
        for (int j = 0; j < J; ++j)
#pragma unroll
            for (int r = 0; r < 4; ++r)
                atomicAdd(&s_lds[bcol][j * 16 + kg * 4 + r], s_acc[j][r]);
    }
    __syncthreads();

    for (int t = tid; t < BT * JD; t += RTH) {
        const int bb = t / JD, p = t % JD;
        S_part[((size_t)icb * BATCH + btile * BT + bb) * JD + p] = s_lds[bb][p];
    }
}

// mode: 0 -> V = v, 1 -> V += v, 2 -> out = v
__global__ __launch_bounds__(256) void squash_kernel(
    const float* __restrict__ S_part, float* __restrict__ V,
    float* __restrict__ out, int mode)
{
    const int t = blockIdx.x * 256 + threadIdx.x;  // BATCH*JD threads
    float s = 0.f;
#pragma unroll
    for (int ic = 0; ic < NIC; ic++)
        s += S_part[(size_t)ic * BATCH * JD + t];
    float sq = s * s;
    sq += __shfl_xor(sq, 1);
    sq += __shfl_xor(sq, 2);
    sq += __shfl_xor(sq, 4);
    sq += __shfl_xor(sq, 8);
    const float v = s * sq / ((1.f + sq) * sqrtf(sq + 1e-8f));
    if (mode == 0)      V[t] = v;
    else if (mode == 1) V[t] += v;
    else                out[t] = v;
}

extern "C" void kernel_launch(void* const* d_in, const int* in_sizes, int n_in,
                              void* d_out, int out_size, void* d_ws, size_t ws_size,
                              hipStream_t stream)
{
    const float* X = (const float*)d_in[0];   // [512][1152][8]
    const float* W = (const float*)d_in[1];   // [1152][10][16][8]
    float* out = (float*)d_out;               // [512][10][16]

    // ws: S_part[16][512][160] f32 (5.24MB) | V[512][160] f32 | Wb bf16 (2.95MB)
    //   | Xb bf16 [1152][512][8] (9.44MB) | zb (64B zeros)   total ~18.0 MB
    float* S_part = (float*)d_ws;
    float* V      = S_part + (size_t)NIC * BATCH * JD;
    short* Wb     = (short*)(V + (size_t)BATCH * JD);
    short* Xb     = Wb + (size_t)IN_CAPS * JD * 8;
    short* zb     = Xb + (size_t)IN_CAPS * BATCH * 8;

    const dim3 rg(NBT * NIC), rb(RTH);        // 512 blocks x 4 waves
    const dim3 sg(BATCH * JD / 256), sb(256); // 320 blocks

    convert_w<<<dim3(720), dim3(256), 0, stream>>>(W, Wb, zb);
    transpose_x<<<dim3((IN_CAPS / TI) * (BATCH / TB)), dim3(256), 0, stream>>>(X, Xb);

    route_kernel<0><<<rg, rb, 0, stream>>>(Xb, Wb, zb, V, S_part);
    squash_kernel<<<sg, sb, 0, stream>>>(S_part, V, out, 0);   // V = v0
    route_kernel<1><<<rg, rb, 0, stream>>>(Xb, Wb, zb, V, S_part);
    squash_kernel<<<sg, sb, 0, stream>>>(S_part, V, out, 1);   // V += v1
    route_kernel<1><<<rg, rb, 0, stream>>>(Xb, Wb, zb, V, S_part);
    squash_kernel<<<sg, sb, 0, stream>>>(S_part, V, out, 2);   // out = v2
}